// Round 11
// baseline (327.296 us; speedup 1.0000x reference)
//
#include <hip/hip_runtime.h>

// ComplexAttention: B=4, S=2048, D=1024. Reduces to single-head attention with
// head_dim 2*D=2048:  Q/K/V = X@W^T+b ; S = Q@K^T/32 ; P = softmax(S) ; O = P@V ;
// out = O@Wo^T + bo.  GEMMs: 256x(NH*128) bf16 MFMA, ONE barrier per K-tile.
// R11: (a) segment = whole K-tile {reads+MMs ∥ stage other buf; vmcnt(0); BAR}.
//   RAW: tile t staged in segment t-1; each wave vmcnt(0)'s its own stage loads
//   BEFORE the barrier -> after BAR all waves' chunks visible (lead ~1 segment).
//   WAR: segment stages only the buf it is NOT reading; reads are consumed by
//   MFMAs (auto-lgkm) before the wave's barrier -> post-BAR restage can't overtake.
//   Waves may drift a whole K-tile -> LDS bursts overlap other waves' MFMA.
// (b) NH=1 variant (256x128 tile) for the final projection: N=1024 -> 256 blocks.

typedef short  bf16x8 __attribute__((ext_vector_type(8)));
typedef float  f32x4  __attribute__((ext_vector_type(4)));
typedef unsigned short u16;

typedef __attribute__((address_space(3))) void       lds_void;
typedef const __attribute__((address_space(1))) void g_void;

__device__ __forceinline__ u16 f2bf(float f) {
  union { float f; unsigned u; } v; v.f = f;
  unsigned r = v.u + 0x7FFFu + ((v.u >> 16) & 1u);   // round-to-nearest-even
  return (u16)(r >> 16);
}

// ---------------- fp32 -> bf16 convert (vectorized) ----------------
__global__ __launch_bounds__(256) void cvt_f32_bf16(const float* __restrict__ in,
                                                    u16* __restrict__ out, int n4) {
  int i = blockIdx.x * 256 + threadIdx.x;
  if (i >= n4) return;
  const float4 v = ((const float4*)in)[i];
  union { u16 us[4]; unsigned long long ll; } u;
  u.us[0] = f2bf(v.x); u.us[1] = f2bf(v.y); u.us[2] = f2bf(v.z); u.us[3] = f2bf(v.w);
  ((unsigned long long*)out)[i] = u.ll;
}

// ---------------- 256x(NH*128) NT GEMM, 1 barrier / K-tile ----------------
// C[m,n] = alpha * sum_k A[m,k]*B[n,k] (+ bias[n]).  A,B bf16 row-major (K contig).
// CMODE: 0 = fp32 C, 1 = bf16 C, 2 = bf16 transposed-V write Vt[b][n][t].
// NH: B halves per tile (2 -> 256-wide, 1 -> 128-wide).  512 thr = 8 waves (2Mx4N);
// per-wave 128x(NH*32); BK=64; LDS dbuf; XOR swizzle; setprio around MFMA.
template<int CMODE, bool BIAS, int NH>
__global__ __launch_bounds__(512, 2) void gemm256(const u16* __restrict__ A,
                                                  const u16* __restrict__ B,
                                                  void* __restrict__ Cv,
                                                  const float* __restrict__ bias,
                                                  int K, int lda, int ldb, int ldc,
                                                  long bsA, long bsB, long bsC,
                                                  float alpha)
{
  __shared__ u16 sm[65536];                  // A: [2][256][64] @ 0 ; B @ 32768
  const int bz = blockIdx.z;
  const u16* Ab = A + (long)bz * bsA;
  const u16* Bb = B + (long)bz * bsB;
  const int m0 = blockIdx.y * 256, n0 = blockIdx.x * (NH * 128);
  const int tid = threadIdx.x, lane = tid & 63, w = tid >> 6;
  const int wmr = w >> 2, wnr = w & 3;
  const int fr = lane & 15, ko = lane >> 4;

  f32x4 acc[8][4] = {};
  bf16x8 afA[8], afB[8], bfA[4], bfB[4];

  auto STAGE = [&](int dbuf, int half, int t, bool isA) {
    const u16* src = isA ? Ab : Bb;
    const int ld = isA ? lda : ldb;
    const int r0 = (isA ? m0 : n0) + half * 128;
    u16* lb = sm + (isA ? 0 : 32768) + dbuf * 16384 + half * 8192;
#pragma unroll
    for (int q = 0; q < 2; ++q) {
      const int slot = q * 512 + w * 64 + lane;
      const int rl = slot >> 3, cc = slot & 7;
      const int c = cc ^ (rl & 7);
      __builtin_amdgcn_global_load_lds(
          (g_void*)(src + (long)(r0 + rl) * ld + t * 64 + c * 8),
          (lds_void*)(lb + q * 4096 + w * 512), 16, 0, 0);
    }
  };
  auto LDA_f = [&](bf16x8* dst, int dbuf, int mh) {
#pragma unroll
    for (int mi = 0; mi < 4; ++mi)
#pragma unroll
      for (int kk = 0; kk < 2; ++kk) {
        const int r = wmr * 128 + mh * 64 + mi * 16 + fr;
        const int c = kk * 4 + ko;
        dst[mi * 2 + kk] = *(const bf16x8*)(sm + dbuf * 16384 + r * 64 + ((c ^ (r & 7)) * 8));
      }
  };
  auto LDB_f = [&](bf16x8* dst, int dbuf, int nh) {
#pragma unroll
    for (int ni = 0; ni < 2; ++ni)
#pragma unroll
      for (int kk = 0; kk < 2; ++kk) {
        const int r = wnr * (NH * 32) + nh * 32 + ni * 16 + fr;
        const int c = kk * 4 + ko;
        dst[ni * 2 + kk] = *(const bf16x8*)(sm + 32768 + dbuf * 16384 + r * 64 + ((c ^ (r & 7)) * 8));
      }
  };
  auto MM = [&](const bf16x8* af, const bf16x8* bf, int mb, int nb) {
    __builtin_amdgcn_s_setprio(1);
#pragma unroll
    for (int mi = 0; mi < 4; ++mi)
#pragma unroll
      for (int ni = 0; ni < 2; ++ni)
#pragma unroll
        for (int kk = 0; kk < 2; ++kk)
          acc[mb + mi][nb + ni] = __builtin_amdgcn_mfma_f32_16x16x32_bf16(
              af[mi * 2 + kk], bf[ni * 2 + kk], acc[mb + mi][nb + ni], 0, 0, 0);
    __builtin_amdgcn_s_setprio(0);
  };

  const int nt = K >> 6;

  // prologue: tile 0 -> buf0; own-drain; barrier (all waves drained before BAR).
  STAGE(0, 0, 0, true);  STAGE(0, 1, 0, true);
  STAGE(0, 0, 0, false);
  if constexpr (NH == 2) STAGE(0, 1, 0, false);
  asm volatile("s_waitcnt vmcnt(0)" ::: "memory");
  asm volatile("s_barrier" ::: "memory");

  for (int t = 0; t < nt; ++t) {
    const int d = t & 1, tn = t + 1;
    const bool stg = (tn < nt);
    // reads + MMs for tile t (buf d), staging tile t+1 into buf d^1 interleaved
    LDA_f(afA, d, 0); LDB_f(bfA, d, 0);
    if (stg) { STAGE(d ^ 1, 0, tn, true); STAGE(d ^ 1, 1, tn, true); }
    MM(afA, bfA, 0, 0);                                  // Q00
    if constexpr (NH == 2) {
      LDB_f(bfB, d, 1);
      if (stg) { STAGE(d ^ 1, 0, tn, false); STAGE(d ^ 1, 1, tn, false); }
      MM(afA, bfB, 0, 2);                                // Q01
      LDA_f(afB, d, 1);
      MM(afB, bfB, 4, 2);                                // Q11
      MM(afB, bfA, 4, 0);                                // Q10
    } else {
      LDA_f(afB, d, 1);
      if (stg) STAGE(d ^ 1, 0, tn, false);
      MM(afB, bfA, 4, 0);                                // Q10
    }
    asm volatile("s_waitcnt vmcnt(0)" ::: "memory");     // own stage loads done
    asm volatile("s_barrier" ::: "memory");              // -> all waves' visible
  }

  // epilogue: C/D frag layout col=lane&15, row=(lane>>4)*4+r  (m89-verified)
  const int col = lane & 15, rb = (lane >> 4) * 4;
#pragma unroll
  for (int mi = 0; mi < 8; ++mi) {
#pragma unroll
    for (int ni = 0; ni < 2 * NH; ++ni) {
      const int mg = m0 + wmr * 128 + mi * 16 + rb;
      const int ng = n0 + wnr * (NH * 32) + ni * 16 + col;
      const float bvv = BIAS ? bias[ng] : 0.0f;
      if constexpr (CMODE == 2) {
        u16* Cc = (u16*)Cv;
        const long bb = mg >> 11;
        const int  t  = mg & 2047;
        union { u16 us[4]; unsigned long long ll; } u;
#pragma unroll
        for (int r = 0; r < 4; ++r) u.us[r] = f2bf(acc[mi][ni][r] * alpha + bvv);
        *(unsigned long long*)(Cc + bb * 4194304 + (long)ng * 2048 + t) = u.ll;
      } else if constexpr (CMODE == 1) {
        u16* Cc = (u16*)Cv + (long)bz * bsC;
#pragma unroll
        for (int r = 0; r < 4; ++r)
          Cc[(long)(mg + r) * ldc + ng] = f2bf(acc[mi][ni][r] * alpha + bvv);
      } else {
        float* Cf = (float*)Cv + (long)bz * bsC;
#pragma unroll
        for (int r = 0; r < 4; ++r)
          Cf[(long)(mg + r) * ldc + ng] = acc[mi][ni][r] * alpha + bvv;
      }
    }
  }
}

// ---------------- row softmax: fp32 scores row (2048) -> bf16 P in-place --------
__global__ __launch_bounds__(256) void softmax_rows(float* __restrict__ Sc) {
  const int tid = threadIdx.x;
  const long row = blockIdx.x;
  float* srow = Sc + row * 2048;
  const float4 v0 = ((const float4*)srow)[tid * 2];
  const float4 v1 = ((const float4*)srow)[tid * 2 + 1];
  float mx = fmaxf(fmaxf(fmaxf(v0.x, v0.y), fmaxf(v0.z, v0.w)),
                   fmaxf(fmaxf(v1.x, v1.y), fmaxf(v1.z, v1.w)));
  __shared__ float red[8];
  const int lane = tid & 63, wid = tid >> 6;
#pragma unroll
  for (int off = 32; off; off >>= 1) mx = fmaxf(mx, __shfl_down(mx, off));
  if (!lane) red[wid] = mx;
  __syncthreads();
  mx = fmaxf(fmaxf(red[0], red[1]), fmaxf(red[2], red[3]));
  float e[8];
  e[0] = __expf(v0.x - mx); e[1] = __expf(v0.y - mx);
  e[2] = __expf(v0.z - mx); e[3] = __expf(v0.w - mx);
  e[4] = __expf(v1.x - mx); e[5] = __expf(v1.y - mx);
  e[6] = __expf(v1.z - mx); e[7] = __expf(v1.w - mx);
  float s = e[0] + e[1] + e[2] + e[3] + e[4] + e[5] + e[6] + e[7];
#pragma unroll
  for (int off = 32; off; off >>= 1) s += __shfl_down(s, off);
  if (!lane) red[4 + wid] = s;
  __syncthreads();
  s = red[4] + red[5] + red[6] + red[7];
  const float inv = 1.0f / s;
  union { u16 us[8]; int4 v; } u;
#pragma unroll
  for (int j = 0; j < 8; ++j) u.us[j] = f2bf(e[j] * inv);
  ((int4*)srow)[tid] = u.v;
}

extern "C" void kernel_launch(void* const* d_in, const int* in_sizes, int n_in,
                              void* d_out, int out_size, void* d_ws, size_t ws_size,
                              hipStream_t stream) {
  const float* X  = (const float*)d_in[0];
  const float* Wq = (const float*)d_in[1];
  const float* bq = (const float*)d_in[2];
  const float* Wk = (const float*)d_in[3];
  const float* bk = (const float*)d_in[4];
  const float* Wv = (const float*)d_in[5];
  const float* bv = (const float*)d_in[6];
  const float* Wo = (const float*)d_in[7];
  const float* bo = (const float*)d_in[8];
  float* out = (float*)d_out;

  char* w = (char*)d_ws;
  u16* Xb  = (u16*)w; w += (size_t)8192 * 1024 * 2;
  u16* Wqb = (u16*)w; w += (size_t)2048 * 1024 * 2;
  u16* Wkb = (u16*)w; w += (size_t)2048 * 1024 * 2;
  u16* Wvb = (u16*)w; w += (size_t)2048 * 1024 * 2;
  u16* Wob = (u16*)w; w += (size_t)1024 * 2048 * 2;
  u16* Qb  = (u16*)w; w += (size_t)8192 * 2048 * 2;
  u16* Kb  = (u16*)w; w += (size_t)8192 * 2048 * 2;
  u16* Vt  = (u16*)w; w += (size_t)8192 * 2048 * 2;   // [4][2048 d][2048 t]
  u16* AO  = (u16*)w; w += (size_t)8192 * 2048 * 2;
  float* Sc = (float*)w; w += (size_t)4 * 2048 * 2048 * 4;
  if ((size_t)(w - (char*)d_ws) > ws_size) return;

  cvt_f32_bf16<<<8192, 256, 0, stream>>>(X,  Xb,  8192 * 1024 / 4);
  cvt_f32_bf16<<<2048, 256, 0, stream>>>(Wq, Wqb, 2048 * 1024 / 4);
  cvt_f32_bf16<<<2048, 256, 0, stream>>>(Wk, Wkb, 2048 * 1024 / 4);
  cvt_f32_bf16<<<2048, 256, 0, stream>>>(Wv, Wvb, 2048 * 1024 / 4);
  cvt_f32_bf16<<<2048, 256, 0, stream>>>(Wo, Wob, 1024 * 2048 / 4);

  // projections: M=8192, N=2048, K=1024
  gemm256<1, true, 2><<<dim3(8, 32, 1), 512, 0, stream>>>(Xb, Wqb, Qb, bq,
      1024, 1024, 1024, 2048, 0, 0, 0, 1.0f);
  gemm256<1, true, 2><<<dim3(8, 32, 1), 512, 0, stream>>>(Xb, Wkb, Kb, bk,
      1024, 1024, 1024, 2048, 0, 0, 0, 1.0f);
  gemm256<2, true, 2><<<dim3(8, 32, 1), 512, 0, stream>>>(Xb, Wvb, Vt, bv,
      1024, 1024, 1024, 0, 0, 0, 0, 1.0f);

  // scores: per-batch 2048x2048, K=2048, alpha = 1/sqrt(1024)
  gemm256<0, false, 2><<<dim3(8, 8, 4), 512, 0, stream>>>(Qb, Kb, Sc, nullptr,
      2048, 2048, 2048, 2048, 4194304, 4194304, 4194304, 0.03125f);

  softmax_rows<<<8192, 256, 0, stream>>>(Sc);

  // O = P @ Vt^T : A = bf16 P view of Sc (lda 4096)
  gemm256<1, false, 2><<<dim3(8, 8, 4), 512, 0, stream>>>((u16*)Sc, Vt, AO, nullptr,
      2048, 4096, 2048, 2048, 8388608, 4194304, 4194304, 1.0f);

  // out = AO @ Wo^T + bo : M=8192, N=1024, K=2048, fp32 out -- NH=1 (256x128 tile,
  // grid 256 blocks: N=1024 would leave half the CUs idle at 256-wide tiles)
  gemm256<0, true, 1><<<dim3(8, 32, 1), 512, 0, stream>>>(AO, Wob, out, bo,
      2048, 2048, 2048, 1024, 0, 0, 0, 1.0f);
}